// Round 17
// baseline (217.670 us; speedup 1.0000x reference)
//
#include <hip/hip_runtime.h>
#include <hip/hip_bf16.h>
#include <math.h>

#define HID 1024
#define INTER 8192
#define TT 4096  // tokens = B*S

typedef __bf16 bf16x8 __attribute__((ext_vector_type(8)));
typedef float f32x4 __attribute__((ext_vector_type(4)));

__device__ __forceinline__ void gll16(const void* g, void* l) {
    __builtin_amdgcn_global_load_lds(
        (const __attribute__((address_space(1))) void*)g,
        (__attribute__((address_space(3))) void*)l, 16, 0, 0);
}

// inline-asm LDS read with immediate offset: invisible to SIInsertWaitcnts;
// RAW ordering is ours (counted lgkmcnt/vmcnt + sched_barrier pins).
template <int OFF>
__device__ __forceinline__ bf16x8 ds_read128o(unsigned addr) {
    bf16x8 r;
    asm volatile("ds_read_b128 %0, %1 offset:%c2" : "=v"(r) : "v"(addr), "i"(OFF));
    return r;
}

// ---------------------------------------------------------------------------
// merged prep: role 0 (blocks 0..1023): cast x->bf16 + s[t]=ew0+ew1
//              role 1 (blocks 1024..9215): transpose-cast w1 [1024][8192] -> w1t
//              role 2 (blocks 9216..17407): transpose-cast w2 [8192][1024] -> w2t
// ---------------------------------------------------------------------------
__device__ __forceinline__ void tcast_tile(const float* __restrict__ in,
                                           __hip_bfloat16* __restrict__ out,
                                           int R, int C, int bx, int by, int tid) {
    __shared__ float tile[32][33];
    const int tx = tid & 31, ty = tid >> 5;  // 32x8
    const int br = by * 32, bc = bx * 32;
#pragma unroll
    for (int j = 0; j < 32; j += 8)
        tile[ty + j][tx] = in[(size_t)(br + ty + j) * C + bc + tx];
    __syncthreads();
#pragma unroll
    for (int j = 0; j < 32; j += 8)
        out[(size_t)(bc + ty + j) * R + br + tx] = __float2bfloat16(tile[tx][ty + j]);
}

__global__ void k_prep(const float* __restrict__ x, const float* __restrict__ ew,
                       const float* __restrict__ w1, const float* __restrict__ w2,
                       __hip_bfloat16* __restrict__ xb, float* __restrict__ s,
                       __hip_bfloat16* __restrict__ w1t, __hip_bfloat16* __restrict__ w2t) {
    const int bid = blockIdx.x, tid = threadIdx.x;
    if (bid < 1024) {
        const int n4 = (TT * HID) / 4;
        const int stride = 1024 * 256;
        for (int i = bid * 256 + tid; i < n4; i += stride) {
            float4 v = ((const float4*)x)[i];
            __hip_bfloat16* o = xb + (size_t)i * 4;
            o[0] = __float2bfloat16(v.x);
            o[1] = __float2bfloat16(v.y);
            o[2] = __float2bfloat16(v.z);
            o[3] = __float2bfloat16(v.w);
        }
        for (int t = bid * 256 + tid; t < TT; t += stride)
            s[t] = ew[2 * t] + ew[2 * t + 1];
    } else if (bid < 1024 + 8192) {
        const int b = bid - 1024;  // w1: R=1024, C=8192 -> bx in [0,256), by in [0,32)
        tcast_tile(w1, w1t, HID, INTER, b % 256, b / 256, tid);
    } else {
        const int b = bid - (1024 + 8192);  // w2: R=8192, C=1024 -> bx in [0,32), by in [0,256)
        tcast_tile(w2, w2t, INTER, HID, b % 32, b / 32, tid);
    }
}

// ---------------------------------------------------------------------------
// 256x256 tile (x CSEG sequential column segments per block), BK=64, 8 waves
// (2Mx4N). SINGLE-BARRIER pipelined K-loop (round-16 best-measured config):
// per K-tile issue 24 ds_read_b128 (cluster-ordered, in-order lgkm FIFO) +
// 8 own-chunk gll16 stages (buf nxt) up front; 4 MFMA clusters gated by
// counted lgkmcnt(12/8/0); one per-wave vmcnt(0) + one s_barrier per K-tile.
// CSEG=2 for GEMM1: grid 256 blocks = exactly 1/CU -> ONE occupancy round
// (vs 512 blocks = two sequential rounds each paying fill+drain). Second
// segment's A panel is L2-hot.
// STAGER = READER chunk map; XOR swizzle on pre-swizzled global source +
// swizzled LDS read (rule #21).
// EPI=0: gelu -> bf16 hOut.  EPI=1: unsafeAtomicAdd(s[row]*acc) into fOut.
// ---------------------------------------------------------------------------
template <int EPI, int CSEG>
__global__ __launch_bounds__(512, 2) void k_gemm1b(
    const __hip_bfloat16* __restrict__ A, const __hip_bfloat16* __restrict__ Bt,
    __hip_bfloat16* __restrict__ hOut, float* __restrict__ fOut,
    const float* __restrict__ s, int Kfull, int nt, int Nout) {
    __shared__ __hip_bfloat16 sA[2][2][128][64];  // [buf][half][row][k]
    __shared__ __hip_bfloat16 sB[2][2][128][64];
    const int tid = threadIdx.x;
    const int lane = tid & 63, wid = tid >> 6;
    const int wr = wid >> 2, wc = wid & 3;  // 2x4 wave grid; wave tile 128x64

    // XCD-bijective swizzle; nwg % 8 == 0 by construction.
    const int nwg = gridDim.x * gridDim.y;
    const int wg = blockIdx.y * gridDim.x + blockIdx.x;
    const int swz = (wg & 7) * (nwg >> 3) + (wg >> 3);
    const int brow = (swz / gridDim.x) * 256;
    const int bcol0 = (swz % gridDim.x) * (256 * CSEG);
    const size_t kbase = (size_t)blockIdx.z * ((size_t)nt * 64);

    // --- per-wave staging (stager = reader) ---
    // chunk = 8 rows x 64 cols = 1KB; lane covers row 8q+(lane>>3), granule
    // (lane&7), source granule pre-XOR'd by row&7 (= lane>>3).
    const int colsw = (((lane & 7) ^ (lane >> 3)) << 3);  // elements
    const int qA0 = (wid & 3) * 4;                        // A chunk base
    const int bh = (wid >> 1) & 1;                        // B half this wave reads
    const int qB0 = ((wid & 1) | ((wid >> 2) << 1)) * 4;  // B chunk base
    const __hip_bfloat16* gA2 =
        A + (size_t)(brow + wr * 128 + qA0 * 8 + (lane >> 3)) * Kfull + kbase + colsw;
    const __hip_bfloat16* gB20 =
        Bt + (size_t)(bcol0 + bh * 128 + qB0 * 8 + (lane >> 3)) * Kfull + kbase + colsw;
    char* ldsA2 = (char*)&sA[0][0][0][0] + wr * 16384 + qA0 * 1024;
    char* ldsB2 = (char*)&sB[0][0][0][0] + bh * 16384 + qB0 * 1024;
    const size_t chunkStep = (size_t)8 * Kfull;

    // read-side swizzled LDS byte addresses (32-bit, for asm ds_read)
    const unsigned baseA = (unsigned)(uintptr_t)&sA[0][0][0][0];
    const unsigned baseB = (unsigned)(uintptr_t)&sB[0][0][0][0];
    const unsigned g0 = (((lane >> 4)) ^ (lane & 7)) << 4;
    const unsigned g1 = ((4 + (lane >> 4)) ^ (lane & 7)) << 4;
    const unsigned rdA0 = baseA + wr * 16384 + (lane & 15) * 128 + g0;
    const unsigned rdA1 = baseA + wr * 16384 + (lane & 15) * 128 + g1;
    const unsigned rdB0 = baseB + (wc >> 1) * 16384 + (wc & 1) * 8192 + (lane & 15) * 128 + g0;
    const unsigned rdB1 = baseB + (wc >> 1) * 16384 + (wc & 1) * 8192 + (lane & 15) * 128 + g1;

#define STAGE_A2(bufoff, t)                                                    \
    do {                                                                       \
        _Pragma("unroll") for (int j = 0; j < 4; ++j)                          \
            gll16(gA2 + (size_t)j * chunkStep + (size_t)(t) * 64,              \
                  ldsA2 + (bufoff) + j * 1024);                                \
    } while (0)
#define STAGE_B2(bufoff, t)                                                    \
    do {                                                                       \
        _Pragma("unroll") for (int j = 0; j < 4; ++j)                          \
            gll16(gBseg + (size_t)j * chunkStep + (size_t)(t) * 64,            \
                  ldsB2 + (bufoff) + j * 1024);                                \
    } while (0)
#define PIN() __builtin_amdgcn_sched_barrier(0)
#define BAR()                              \
    do {                                   \
        PIN();                             \
        __builtin_amdgcn_s_barrier();      \
        PIN();                             \
    } while (0)
#define WAIT_LG12() __builtin_amdgcn_s_waitcnt(0xCC7F)  // lgkmcnt(12)
#define WAIT_LG8() __builtin_amdgcn_s_waitcnt(0xC87F)   // lgkmcnt(8)
#define WAIT_LG0() __builtin_amdgcn_s_waitcnt(0xC07F)   // lgkmcnt(0)
#define WAIT_VM0() __builtin_amdgcn_s_waitcnt(0x0F70)   // vmcnt(0)

#pragma unroll 1
    for (int cs = 0; cs < CSEG; ++cs) {
        const __hip_bfloat16* gBseg = gB20 + (size_t)cs * 256 * Kfull;
        const int bcol = bcol0 + cs * 256;

        f32x4 acc[8][4] = {};
        bf16x8 a03[4][2], a47[4][2], b01[2][2], b23[2][2];

        // prologue: tile0 into buf0 (per-wave own halves), full drain once.
        STAGE_A2(0u, 0);
        STAGE_B2(0u, 0);
        WAIT_VM0();
        BAR();

#pragma unroll 1
        for (int i = 0; i < nt; ++i) {
            const unsigned co = (i & 1) ? 32768u : 0u;  // current buf byte offset
            const unsigned no = co ^ 32768u;            // next buf
            const bool full = (i + 1 < nt);
            const unsigned aA0 = rdA0 + co, aA1 = rdA1 + co;
            const unsigned aB0 = rdB0 + co, aB1 = rdB1 + co;

            // ---- issue cluster-1 reads: a03 (8) + b01 (4)
            a03[0][0] = ds_read128o<0>(aA0);
            a03[0][1] = ds_read128o<0>(aA1);
            a03[1][0] = ds_read128o<2048>(aA0);
            a03[1][1] = ds_read128o<2048>(aA1);
            a03[2][0] = ds_read128o<4096>(aA0);
            a03[2][1] = ds_read128o<4096>(aA1);
            a03[3][0] = ds_read128o<6144>(aA0);
            a03[3][1] = ds_read128o<6144>(aA1);
            b01[0][0] = ds_read128o<0>(aB0);
            b01[0][1] = ds_read128o<0>(aB1);
            b01[1][0] = ds_read128o<2048>(aB0);
            b01[1][1] = ds_read128o<2048>(aB1);
            // ---- cluster-2 reads: b23 (4)
            b23[0][0] = ds_read128o<4096>(aB0);
            b23[0][1] = ds_read128o<4096>(aB1);
            b23[1][0] = ds_read128o<6144>(aB0);
            b23[1][1] = ds_read128o<6144>(aB1);
            // ---- cluster-3 reads: a47 (8)
            a47[0][0] = ds_read128o<8192>(aA0);
            a47[0][1] = ds_read128o<8192>(aA1);
            a47[1][0] = ds_read128o<10240>(aA0);
            a47[1][1] = ds_read128o<10240>(aA1);
            a47[2][0] = ds_read128o<12288>(aA0);
            a47[2][1] = ds_read128o<12288>(aA1);
            a47[3][0] = ds_read128o<14336>(aA0);
            a47[3][1] = ds_read128o<14336>(aA1);

            // ---- issue next tile's stages (vmcnt only; ~1 full iter of slack)
            if (full) {
                STAGE_A2(no, i + 1);
                STAGE_B2(no, i + 1);
            }

            __builtin_amdgcn_s_setprio(1);
            // ---- cluster 1: m0-3 x n0-1 (first 12 reads done <=> lgkm<=12)
            WAIT_LG12();
            PIN();
#pragma unroll
            for (int ks = 0; ks < 2; ++ks)
#pragma unroll
                for (int m = 0; m < 4; ++m)
#pragma unroll
                    for (int n = 0; n < 2; ++n)
                        acc[m][n] = __builtin_amdgcn_mfma_f32_16x16x32_bf16(
                            a03[m][ks], b01[n][ks], acc[m][n], 0, 0, 0);
            PIN();
            // ---- cluster 2: m0-3 x n2-3 (first 16 done <=> lgkm<=8)
            WAIT_LG8();
            PIN();
#pragma unroll
            for (int ks = 0; ks < 2; ++ks)
#pragma unroll
                for (int m = 0; m < 4; ++m)
#pragma unroll
                    for (int n = 0; n < 2; ++n)
                        acc[m][2 + n] = __builtin_amdgcn_mfma_f32_16x16x32_bf16(
                            a03[m][ks], b23[n][ks], acc[m][2 + n], 0, 0, 0);
            PIN();
            // ---- clusters 3+4: m4-7 x n2-3, m4-7 x n0-1 (all reads done)
            WAIT_LG0();
            PIN();
#pragma unroll
            for (int ks = 0; ks < 2; ++ks)
#pragma unroll
                for (int m = 0; m < 4; ++m)
#pragma unroll
                    for (int n = 0; n < 2; ++n)
                        acc[4 + m][2 + n] = __builtin_amdgcn_mfma_f32_16x16x32_bf16(
                            a47[m][ks], b23[n][ks], acc[4 + m][2 + n], 0, 0, 0);
#pragma unroll
            for (int ks = 0; ks < 2; ++ks)
#pragma unroll
                for (int m = 0; m < 4; ++m)
#pragma unroll
                    for (int n = 0; n < 2; ++n)
                        acc[4 + m][n] = __builtin_amdgcn_mfma_f32_16x16x32_bf16(
                            a47[m][ks], b01[n][ks], acc[4 + m][n], 0, 0, 0);
            __builtin_amdgcn_s_setprio(0);
            PIN();
            // ---- tile boundary: own stages (issued at iter top) must be in
            // LDS before anyone reads buf nxt next iter; then block-wide sync.
            WAIT_VM0();
            BAR();
        }

        // epilogue (stores are vmem-FIFO ordered ahead of the next segment's
        // stages, so the next prologue's WAIT_VM0 also covers them)
        const int orow = brow + wr * 128 + ((lane >> 4) << 2);
        const int ocol = bcol + wc * 64 + (lane & 15);
#pragma unroll
        for (int m = 0; m < 8; ++m) {
#pragma unroll
            for (int j = 0; j < 4; ++j) {
                const int r = orow + m * 16 + j;
                const size_t ro = (size_t)r * Nout;
                if (EPI == 0) {
#pragma unroll
                    for (int n = 0; n < 4; ++n) {
                        float v = acc[m][n][j];
                        float u = 1.5957691216057308f * (v + 0.044715f * v * v * v);
                        float g = v / (1.0f + __expf(-u));
                        hOut[ro + ocol + n * 16] = __float2bfloat16(g);
                    }
                } else {
                    const float sc = s[r];
#pragma unroll
                    for (int n = 0; n < 4; ++n)
                        unsafeAtomicAdd(&fOut[ro + ocol + n * 16], sc * acc[m][n][j]);
                }
            }
        }
    }
#undef STAGE_A2
#undef STAGE_B2
#undef PIN
#undef BAR
#undef WAIT_LG12
#undef WAIT_LG8
#undef WAIT_LG0
#undef WAIT_VM0
}

extern "C" void kernel_launch(void* const* d_in, const int* in_sizes, int n_in,
                              void* d_out, int out_size, void* d_ws, size_t ws_size,
                              hipStream_t stream) {
    const float* x = (const float*)d_in[0];
    // d_in[1] = scores (unused), d_in[3] = top_experts (unused)
    const float* ew = (const float*)d_in[2];
    const float* w1 = (const float*)d_in[4];
    const float* w2 = (const float*)d_in[5];
    float* out = (float*)d_out;

    char* ws = (char*)d_ws;
    float* s = (float*)ws;                                                    // 16 KB
    __hip_bfloat16* xb = (__hip_bfloat16*)(ws + 16384);                       // 8 MB
    __hip_bfloat16* w1t = (__hip_bfloat16*)(ws + 16384 + 8388608);            // 16 MB
    __hip_bfloat16* w2t = (__hip_bfloat16*)(ws + 16384 + 8388608 + 16777216); // 16 MB
    __hip_bfloat16* h = (__hip_bfloat16*)(ws + 16384 + 8388608 + 2 * 16777216); // 64 MB

    // merged prep: cast+scale (1024 blocks) + w1 transpose (8192) + w2 transpose (8192)
    k_prep<<<1024 + 8192 + 8192, 256, 0, stream>>>(x, ew, w1, w2, xb, s, w1t, w2t);

    // GEMM1: [4096 x 1024] x [1024 x 8192] -> h (gelu, bf16)
    // CSEG=2: 16 x 16 = 256 blocks (exactly 1/CU -> single occupancy round)
    dim3 g1(INTER / 512, TT / 256, 1);
    k_gemm1b<0, 2><<<g1, 512, 0, stream>>>(xb, w1t, h, nullptr, nullptr, HID, HID / 64, INTER);

    // GEMM2: [4096 x 8192] x [8192 x 1024] -> out (f32, split-K=4 atomic combine)
    hipMemsetAsync(out, 0, (size_t)TT * HID * sizeof(float), stream);
    dim3 g2(HID / 256, TT / 256, 4);  // 4 x 16 x 4 = 256 blocks
    k_gemm1b<1, 1><<<g2, 512, 0, stream>>>(h, w2t, nullptr, out, s, INTER, 2048 / 64, HID);
}

// Round 18
// 198.806 us; speedup vs baseline: 1.0949x; 1.0949x over previous
//
#include <hip/hip_runtime.h>
#include <hip/hip_bf16.h>
#include <math.h>

#define HID 1024
#define INTER 8192
#define TT 4096  // tokens = B*S

typedef __bf16 bf16x8 __attribute__((ext_vector_type(8)));
typedef float f32x4 __attribute__((ext_vector_type(4)));

__device__ __forceinline__ void gll16(const void* g, void* l) {
    __builtin_amdgcn_global_load_lds(
        (const __attribute__((address_space(1))) void*)g,
        (__attribute__((address_space(3))) void*)l, 16, 0, 0);
}

// inline-asm LDS read with immediate offset: invisible to SIInsertWaitcnts;
// RAW ordering is ours (counted lgkmcnt/vmcnt + sched_barrier pins).
template <int OFF>
__device__ __forceinline__ bf16x8 ds_read128o(unsigned addr) {
    bf16x8 r;
    asm volatile("ds_read_b128 %0, %1 offset:%c2" : "=v"(r) : "v"(addr), "i"(OFF));
    return r;
}

// ---------------------------------------------------------------------------
// merged prep: role 0 (blocks 0..1023): cast x->bf16 + s[t]=ew0+ew1
//              role 1 (blocks 1024..9215): transpose-cast w1 [1024][8192] -> w1t
//              role 2 (blocks 9216..17407): transpose-cast w2 [8192][1024] -> w2t
// ---------------------------------------------------------------------------
__device__ __forceinline__ void tcast_tile(const float* __restrict__ in,
                                           __hip_bfloat16* __restrict__ out,
                                           int R, int C, int bx, int by, int tid) {
    __shared__ float tile[32][33];
    const int tx = tid & 31, ty = tid >> 5;  // 32x8
    const int br = by * 32, bc = bx * 32;
#pragma unroll
    for (int j = 0; j < 32; j += 8)
        tile[ty + j][tx] = in[(size_t)(br + ty + j) * C + bc + tx];
    __syncthreads();
#pragma unroll
    for (int j = 0; j < 32; j += 8)
        out[(size_t)(bc + ty + j) * R + br + tx] = __float2bfloat16(tile[tx][ty + j]);
}

__global__ void k_prep(const float* __restrict__ x, const float* __restrict__ ew,
                       const float* __restrict__ w1, const float* __restrict__ w2,
                       __hip_bfloat16* __restrict__ xb, float* __restrict__ s,
                       __hip_bfloat16* __restrict__ w1t, __hip_bfloat16* __restrict__ w2t) {
    const int bid = blockIdx.x, tid = threadIdx.x;
    if (bid < 1024) {
        const int n4 = (TT * HID) / 4;
        const int stride = 1024 * 256;
        for (int i = bid * 256 + tid; i < n4; i += stride) {
            float4 v = ((const float4*)x)[i];
            __hip_bfloat16* o = xb + (size_t)i * 4;
            o[0] = __float2bfloat16(v.x);
            o[1] = __float2bfloat16(v.y);
            o[2] = __float2bfloat16(v.z);
            o[3] = __float2bfloat16(v.w);
        }
        for (int t = bid * 256 + tid; t < TT; t += stride)
            s[t] = ew[2 * t] + ew[2 * t + 1];
    } else if (bid < 1024 + 8192) {
        const int b = bid - 1024;  // w1: R=1024, C=8192 -> bx in [0,256), by in [0,32)
        tcast_tile(w1, w1t, HID, INTER, b % 256, b / 256, tid);
    } else {
        const int b = bid - (1024 + 8192);  // w2: R=8192, C=1024 -> bx in [0,32), by in [0,256)
        tcast_tile(w2, w2t, INTER, HID, b % 32, b / 32, tid);
    }
}

// ---------------------------------------------------------------------------
// 256x256 tile, BK=64, 8 waves (2Mx4N). SINGLE-BARRIER pipelined K-loop
// (best-measured config, rounds 12/14/16: 198.7-199.2 us): per K-tile issue
// 24 ds_read_b128 (cluster-ordered, in-order lgkm FIFO) + 8 own-chunk gll16
// stages (buf nxt) up front; 4 MFMA clusters gated by counted
// lgkmcnt(12/8/0); one per-wave vmcnt(0) (own stages) + one s_barrier per
// K-tile.
// STAGER = READER chunk map: wave stages exactly the A-half / B-half it
// reads -> per-wave vmcnt ledger is self-contained.
// XOR swizzle on pre-swizzled global source + swizzled LDS read (rule #21).
// EPI=0: gelu -> bf16 hOut.  EPI=1: unsafeAtomicAdd(s[row]*acc) into fOut.
// ---------------------------------------------------------------------------
template <int EPI>
__global__ __launch_bounds__(512, 2) void k_gemm1b(
    const __hip_bfloat16* __restrict__ A, const __hip_bfloat16* __restrict__ Bt,
    __hip_bfloat16* __restrict__ hOut, float* __restrict__ fOut,
    const float* __restrict__ s, int Kfull, int nt, int Nout) {
    __shared__ __hip_bfloat16 sA[2][2][128][64];  // [buf][half][row][k]
    __shared__ __hip_bfloat16 sB[2][2][128][64];
    const int tid = threadIdx.x;
    const int lane = tid & 63, wid = tid >> 6;
    const int wr = wid >> 2, wc = wid & 3;  // 2x4 wave grid; wave tile 128x64

    // XCD-bijective swizzle; nwg % 8 == 0 by construction.
    const int nwg = gridDim.x * gridDim.y;
    const int wg = blockIdx.y * gridDim.x + blockIdx.x;
    const int swz = (wg & 7) * (nwg >> 3) + (wg >> 3);
    const int brow = (swz / gridDim.x) * 256;
    const int bcol = (swz % gridDim.x) * 256;
    const size_t kbase = (size_t)blockIdx.z * ((size_t)nt * 64);

    // --- per-wave staging (stager = reader) ---
    // chunk = 8 rows x 64 cols = 1KB; lane covers row 8q+(lane>>3), granule
    // (lane&7), source granule pre-XOR'd by row&7 (= lane>>3).
    const int colsw = (((lane & 7) ^ (lane >> 3)) << 3);  // elements
    const int qA0 = (wid & 3) * 4;                        // A chunk base
    const int bh = (wid >> 1) & 1;                        // B half this wave reads
    const int qB0 = ((wid & 1) | ((wid >> 2) << 1)) * 4;  // B chunk base
    const __hip_bfloat16* gA2 =
        A + (size_t)(brow + wr * 128 + qA0 * 8 + (lane >> 3)) * Kfull + kbase + colsw;
    const __hip_bfloat16* gB2 =
        Bt + (size_t)(bcol + bh * 128 + qB0 * 8 + (lane >> 3)) * Kfull + kbase + colsw;
    char* ldsA2 = (char*)&sA[0][0][0][0] + wr * 16384 + qA0 * 1024;
    char* ldsB2 = (char*)&sB[0][0][0][0] + bh * 16384 + qB0 * 1024;
    const size_t chunkStep = (size_t)8 * Kfull;

    // read-side swizzled LDS byte addresses (32-bit, for asm ds_read)
    const unsigned baseA = (unsigned)(uintptr_t)&sA[0][0][0][0];
    const unsigned baseB = (unsigned)(uintptr_t)&sB[0][0][0][0];
    const unsigned g0 = (((lane >> 4)) ^ (lane & 7)) << 4;
    const unsigned g1 = ((4 + (lane >> 4)) ^ (lane & 7)) << 4;
    const unsigned rdA0 = baseA + wr * 16384 + (lane & 15) * 128 + g0;
    const unsigned rdA1 = baseA + wr * 16384 + (lane & 15) * 128 + g1;
    const unsigned rdB0 = baseB + (wc >> 1) * 16384 + (wc & 1) * 8192 + (lane & 15) * 128 + g0;
    const unsigned rdB1 = baseB + (wc >> 1) * 16384 + (wc & 1) * 8192 + (lane & 15) * 128 + g1;

    f32x4 acc[8][4] = {};
    bf16x8 a03[4][2], a47[4][2], b01[2][2], b23[2][2];

#define STAGE_A2(bufoff, t)                                                    \
    do {                                                                       \
        _Pragma("unroll") for (int j = 0; j < 4; ++j)                          \
            gll16(gA2 + (size_t)j * chunkStep + (size_t)(t) * 64,              \
                  ldsA2 + (bufoff) + j * 1024);                                \
    } while (0)
#define STAGE_B2(bufoff, t)                                                    \
    do {                                                                       \
        _Pragma("unroll") for (int j = 0; j < 4; ++j)                          \
            gll16(gB2 + (size_t)j * chunkStep + (size_t)(t) * 64,              \
                  ldsB2 + (bufoff) + j * 1024);                                \
    } while (0)
#define PIN() __builtin_amdgcn_sched_barrier(0)
#define BAR()                              \
    do {                                   \
        PIN();                             \
        __builtin_amdgcn_s_barrier();      \
        PIN();                             \
    } while (0)
#define WAIT_LG12() __builtin_amdgcn_s_waitcnt(0xCC7F)  // lgkmcnt(12)
#define WAIT_LG8() __builtin_amdgcn_s_waitcnt(0xC87F)   // lgkmcnt(8)
#define WAIT_LG0() __builtin_amdgcn_s_waitcnt(0xC07F)   // lgkmcnt(0)
#define WAIT_VM0() __builtin_amdgcn_s_waitcnt(0x0F70)   // vmcnt(0)

    // prologue: tile0 into buf0 (per-wave own halves), full drain once.
    STAGE_A2(0u, 0);
    STAGE_B2(0u, 0);
    WAIT_VM0();
    BAR();

#pragma unroll 1
    for (int i = 0; i < nt; ++i) {
        const unsigned co = (i & 1) ? 32768u : 0u;  // current buf byte offset
        const unsigned no = co ^ 32768u;            // next buf
        const bool full = (i + 1 < nt);
        const unsigned aA0 = rdA0 + co, aA1 = rdA1 + co;
        const unsigned aB0 = rdB0 + co, aB1 = rdB1 + co;

        // ---- issue cluster-1 reads: a03 (8) + b01 (4)
        a03[0][0] = ds_read128o<0>(aA0);
        a03[0][1] = ds_read128o<0>(aA1);
        a03[1][0] = ds_read128o<2048>(aA0);
        a03[1][1] = ds_read128o<2048>(aA1);
        a03[2][0] = ds_read128o<4096>(aA0);
        a03[2][1] = ds_read128o<4096>(aA1);
        a03[3][0] = ds_read128o<6144>(aA0);
        a03[3][1] = ds_read128o<6144>(aA1);
        b01[0][0] = ds_read128o<0>(aB0);
        b01[0][1] = ds_read128o<0>(aB1);
        b01[1][0] = ds_read128o<2048>(aB0);
        b01[1][1] = ds_read128o<2048>(aB1);
        // ---- cluster-2 reads: b23 (4)
        b23[0][0] = ds_read128o<4096>(aB0);
        b23[0][1] = ds_read128o<4096>(aB1);
        b23[1][0] = ds_read128o<6144>(aB0);
        b23[1][1] = ds_read128o<6144>(aB1);
        // ---- cluster-3 reads: a47 (8)
        a47[0][0] = ds_read128o<8192>(aA0);
        a47[0][1] = ds_read128o<8192>(aA1);
        a47[1][0] = ds_read128o<10240>(aA0);
        a47[1][1] = ds_read128o<10240>(aA1);
        a47[2][0] = ds_read128o<12288>(aA0);
        a47[2][1] = ds_read128o<12288>(aA1);
        a47[3][0] = ds_read128o<14336>(aA0);
        a47[3][1] = ds_read128o<14336>(aA1);

        // ---- issue next tile's stages (vmcnt only; ~1 full iter of slack)
        if (full) {
            STAGE_A2(no, i + 1);
            STAGE_B2(no, i + 1);
        }

        __builtin_amdgcn_s_setprio(1);
        // ---- cluster 1: m0-3 x n0-1 (first 12 reads done <=> lgkm<=12)
        WAIT_LG12();
        PIN();
#pragma unroll
        for (int ks = 0; ks < 2; ++ks)
#pragma unroll
            for (int m = 0; m < 4; ++m)
#pragma unroll
                for (int n = 0; n < 2; ++n)
                    acc[m][n] = __builtin_amdgcn_mfma_f32_16x16x32_bf16(
                        a03[m][ks], b01[n][ks], acc[m][n], 0, 0, 0);
        PIN();
        // ---- cluster 2: m0-3 x n2-3 (first 16 done <=> lgkm<=8)
        WAIT_LG8();
        PIN();
#pragma unroll
        for (int ks = 0; ks < 2; ++ks)
#pragma unroll
            for (int m = 0; m < 4; ++m)
#pragma unroll
                for (int n = 0; n < 2; ++n)
                    acc[m][2 + n] = __builtin_amdgcn_mfma_f32_16x16x32_bf16(
                        a03[m][ks], b23[n][ks], acc[m][2 + n], 0, 0, 0);
        PIN();
        // ---- clusters 3+4: m4-7 x n2-3, m4-7 x n0-1 (all reads done)
        WAIT_LG0();
        PIN();
#pragma unroll
        for (int ks = 0; ks < 2; ++ks)
#pragma unroll
            for (int m = 0; m < 4; ++m)
#pragma unroll
                for (int n = 0; n < 2; ++n)
                    acc[4 + m][2 + n] = __builtin_amdgcn_mfma_f32_16x16x32_bf16(
                        a47[m][ks], b23[n][ks], acc[4 + m][2 + n], 0, 0, 0);
#pragma unroll
        for (int ks = 0; ks < 2; ++ks)
#pragma unroll
            for (int m = 0; m < 4; ++m)
#pragma unroll
                for (int n = 0; n < 2; ++n)
                    acc[4 + m][n] = __builtin_amdgcn_mfma_f32_16x16x32_bf16(
                        a47[m][ks], b01[n][ks], acc[4 + m][n], 0, 0, 0);
        __builtin_amdgcn_s_setprio(0);
        PIN();
        // ---- tile boundary: own stages (issued at iter top) must be in LDS
        // before anyone reads buf nxt next iter; then block-wide sync.
        WAIT_VM0();
        BAR();
    }

    // epilogue
    const int orow = brow + wr * 128 + ((lane >> 4) << 2);
    const int ocol = bcol + wc * 64 + (lane & 15);
#pragma unroll
    for (int m = 0; m < 8; ++m) {
#pragma unroll
        for (int j = 0; j < 4; ++j) {
            const int r = orow + m * 16 + j;
            const size_t ro = (size_t)r * Nout;
            if (EPI == 0) {
#pragma unroll
                for (int n = 0; n < 4; ++n) {
                    float v = acc[m][n][j];
                    float u = 1.5957691216057308f * (v + 0.044715f * v * v * v);
                    float g = v / (1.0f + __expf(-u));
                    hOut[ro + ocol + n * 16] = __float2bfloat16(g);
                }
            } else {
                const float sc = s[r];
#pragma unroll
                for (int n = 0; n < 4; ++n)
                    unsafeAtomicAdd(&fOut[ro + ocol + n * 16], sc * acc[m][n][j]);
            }
        }
    }
#undef STAGE_A2
#undef STAGE_B2
#undef PIN
#undef BAR
#undef WAIT_LG12
#undef WAIT_LG8
#undef WAIT_LG0
#undef WAIT_VM0
}

extern "C" void kernel_launch(void* const* d_in, const int* in_sizes, int n_in,
                              void* d_out, int out_size, void* d_ws, size_t ws_size,
                              hipStream_t stream) {
    const float* x = (const float*)d_in[0];
    // d_in[1] = scores (unused), d_in[3] = top_experts (unused)
    const float* ew = (const float*)d_in[2];
    const float* w1 = (const float*)d_in[4];
    const float* w2 = (const float*)d_in[5];
    float* out = (float*)d_out;

    char* ws = (char*)d_ws;
    float* s = (float*)ws;                                                    // 16 KB
    __hip_bfloat16* xb = (__hip_bfloat16*)(ws + 16384);                       // 8 MB
    __hip_bfloat16* w1t = (__hip_bfloat16*)(ws + 16384 + 8388608);            // 16 MB
    __hip_bfloat16* w2t = (__hip_bfloat16*)(ws + 16384 + 8388608 + 16777216); // 16 MB
    __hip_bfloat16* h = (__hip_bfloat16*)(ws + 16384 + 8388608 + 2 * 16777216); // 64 MB

    // merged prep: cast+scale (1024 blocks) + w1 transpose (8192) + w2 transpose (8192)
    k_prep<<<1024 + 8192 + 8192, 256, 0, stream>>>(x, ew, w1, w2, xb, s, w1t, w2t);

    // GEMM1: [4096 x 1024] x [1024 x 8192] -> h (gelu, bf16)
    dim3 g1(INTER / 256, TT / 256, 1);  // 32 x 16
    k_gemm1b<0><<<g1, 512, 0, stream>>>(xb, w1t, h, nullptr, nullptr, HID, HID / 64, INTER);

    // GEMM2: [4096 x 8192] x [8192 x 1024] -> out (f32, split-K=4 atomic combine)
    hipMemsetAsync(out, 0, (size_t)TT * HID * sizeof(float), stream);
    dim3 g2(HID / 256, TT / 256, 4);  // 4 x 16 x 4 = 256 blocks
    k_gemm1b<1><<<g2, 512, 0, stream>>>(h, w2t, nullptr, out, s, INTER, 2048 / 64, HID);
}

// Round 19
// 196.588 us; speedup vs baseline: 1.1072x; 1.0113x over previous
//
#include <hip/hip_runtime.h>
#include <hip/hip_bf16.h>
#include <math.h>

#define HID 1024
#define INTER 8192
#define TT 4096  // tokens = B*S

typedef __bf16 bf16x8 __attribute__((ext_vector_type(8)));
typedef float f32x4 __attribute__((ext_vector_type(4)));

__device__ __forceinline__ void gll16(const void* g, void* l) {
    __builtin_amdgcn_global_load_lds(
        (const __attribute__((address_space(1))) void*)g,
        (__attribute__((address_space(3))) void*)l, 16, 0, 0);
}

// inline-asm LDS read with immediate offset: invisible to SIInsertWaitcnts;
// RAW ordering is ours (counted lgkmcnt/vmcnt + sched_barrier pins).
template <int OFF>
__device__ __forceinline__ bf16x8 ds_read128o(unsigned addr) {
    bf16x8 r;
    asm volatile("ds_read_b128 %0, %1 offset:%c2" : "=v"(r) : "v"(addr), "i"(OFF));
    return r;
}

// ---------------------------------------------------------------------------
// merged prep: role 0 (blocks 0..1023): cast x->bf16 + s[t]=ew0+ew1
//              role 1 (blocks 1024..9215): transpose-cast w1 [1024][8192] -> w1t
//              role 2 (blocks 9216..17407): transpose-cast w2 [8192][1024] -> w2t
//              role 3 (blocks 17408..18431): zero d_out (replaces memset dispatch)
// ---------------------------------------------------------------------------
__device__ __forceinline__ void tcast_tile(const float* __restrict__ in,
                                           __hip_bfloat16* __restrict__ out,
                                           int R, int C, int bx, int by, int tid) {
    __shared__ float tile[32][33];
    const int tx = tid & 31, ty = tid >> 5;  // 32x8
    const int br = by * 32, bc = bx * 32;
#pragma unroll
    for (int j = 0; j < 32; j += 8)
        tile[ty + j][tx] = in[(size_t)(br + ty + j) * C + bc + tx];
    __syncthreads();
#pragma unroll
    for (int j = 0; j < 32; j += 8)
        out[(size_t)(bc + ty + j) * R + br + tx] = __float2bfloat16(tile[tx][ty + j]);
}

__global__ void k_prep(const float* __restrict__ x, const float* __restrict__ ew,
                       const float* __restrict__ w1, const float* __restrict__ w2,
                       __hip_bfloat16* __restrict__ xb, float* __restrict__ s,
                       __hip_bfloat16* __restrict__ w1t, __hip_bfloat16* __restrict__ w2t,
                       float* __restrict__ outZ) {
    const int bid = blockIdx.x, tid = threadIdx.x;
    if (bid < 1024) {
        const int n4 = (TT * HID) / 4;
        const int stride = 1024 * 256;
        for (int i = bid * 256 + tid; i < n4; i += stride) {
            float4 v = ((const float4*)x)[i];
            __hip_bfloat16* o = xb + (size_t)i * 4;
            o[0] = __float2bfloat16(v.x);
            o[1] = __float2bfloat16(v.y);
            o[2] = __float2bfloat16(v.z);
            o[3] = __float2bfloat16(v.w);
        }
        for (int t = bid * 256 + tid; t < TT; t += stride)
            s[t] = ew[2 * t] + ew[2 * t + 1];
    } else if (bid < 1024 + 8192) {
        const int b = bid - 1024;  // w1: R=1024, C=8192 -> bx in [0,256), by in [0,32)
        tcast_tile(w1, w1t, HID, INTER, b % 256, b / 256, tid);
    } else if (bid < 1024 + 8192 + 8192) {
        const int b = bid - (1024 + 8192);  // w2: R=8192, C=1024 -> bx in [0,32), by in [0,256)
        tcast_tile(w2, w2t, INTER, HID, b % 32, b / 32, tid);
    } else {
        // role 3: zero out (GEMM2 atomic-combine target); prep completes
        // before GEMM2 launches (stream order), so this replaces the memset.
        const int zb = bid - (1024 + 8192 + 8192);  // [0,1024)
        float4* o4 = (float4*)outZ;
        const int N4 = (TT * HID) / 4;
        for (int i = zb * 256 + tid; i < N4; i += 1024 * 256)
            o4[i] = make_float4(0.f, 0.f, 0.f, 0.f);
    }
}

// ---------------------------------------------------------------------------
// 256x256 tile, BK=64, 8 waves (2Mx4N). SINGLE-BARRIER pipelined K-loop
// (best-measured config, rounds 12/14/16/18: 198.7-199.2 us): per K-tile
// issue 24 ds_read_b128 (cluster-ordered, in-order lgkm FIFO) + 8 own-chunk
// gll16 stages (buf nxt) up front; 4 MFMA clusters gated by counted
// lgkmcnt(12/8/0); one per-wave vmcnt(0) (own stages) + one s_barrier per
// K-tile.
// STAGER = READER chunk map: wave stages exactly the A-half / B-half it
// reads -> per-wave vmcnt ledger is self-contained.
// XOR swizzle on pre-swizzled global source + swizzled LDS read (rule #21).
// EPI=0: gelu -> bf16 hOut.  EPI=1: unsafeAtomicAdd(s[row]*acc) into fOut.
// ---------------------------------------------------------------------------
template <int EPI>
__global__ __launch_bounds__(512, 2) void k_gemm1b(
    const __hip_bfloat16* __restrict__ A, const __hip_bfloat16* __restrict__ Bt,
    __hip_bfloat16* __restrict__ hOut, float* __restrict__ fOut,
    const float* __restrict__ s, int Kfull, int nt, int Nout) {
    __shared__ __hip_bfloat16 sA[2][2][128][64];  // [buf][half][row][k]
    __shared__ __hip_bfloat16 sB[2][2][128][64];
    const int tid = threadIdx.x;
    const int lane = tid & 63, wid = tid >> 6;
    const int wr = wid >> 2, wc = wid & 3;  // 2x4 wave grid; wave tile 128x64

    // XCD-bijective swizzle; nwg % 8 == 0 by construction.
    const int nwg = gridDim.x * gridDim.y;
    const int wg = blockIdx.y * gridDim.x + blockIdx.x;
    const int swz = (wg & 7) * (nwg >> 3) + (wg >> 3);
    const int brow = (swz / gridDim.x) * 256;
    const int bcol = (swz % gridDim.x) * 256;
    const size_t kbase = (size_t)blockIdx.z * ((size_t)nt * 64);

    // --- per-wave staging (stager = reader) ---
    // chunk = 8 rows x 64 cols = 1KB; lane covers row 8q+(lane>>3), granule
    // (lane&7), source granule pre-XOR'd by row&7 (= lane>>3).
    const int colsw = (((lane & 7) ^ (lane >> 3)) << 3);  // elements
    const int qA0 = (wid & 3) * 4;                        // A chunk base
    const int bh = (wid >> 1) & 1;                        // B half this wave reads
    const int qB0 = ((wid & 1) | ((wid >> 2) << 1)) * 4;  // B chunk base
    const __hip_bfloat16* gA2 =
        A + (size_t)(brow + wr * 128 + qA0 * 8 + (lane >> 3)) * Kfull + kbase + colsw;
    const __hip_bfloat16* gB2 =
        Bt + (size_t)(bcol + bh * 128 + qB0 * 8 + (lane >> 3)) * Kfull + kbase + colsw;
    char* ldsA2 = (char*)&sA[0][0][0][0] + wr * 16384 + qA0 * 1024;
    char* ldsB2 = (char*)&sB[0][0][0][0] + bh * 16384 + qB0 * 1024;
    const size_t chunkStep = (size_t)8 * Kfull;

    // read-side swizzled LDS byte addresses (32-bit, for asm ds_read)
    const unsigned baseA = (unsigned)(uintptr_t)&sA[0][0][0][0];
    const unsigned baseB = (unsigned)(uintptr_t)&sB[0][0][0][0];
    const unsigned g0 = (((lane >> 4)) ^ (lane & 7)) << 4;
    const unsigned g1 = ((4 + (lane >> 4)) ^ (lane & 7)) << 4;
    const unsigned rdA0 = baseA + wr * 16384 + (lane & 15) * 128 + g0;
    const unsigned rdA1 = baseA + wr * 16384 + (lane & 15) * 128 + g1;
    const unsigned rdB0 = baseB + (wc >> 1) * 16384 + (wc & 1) * 8192 + (lane & 15) * 128 + g0;
    const unsigned rdB1 = baseB + (wc >> 1) * 16384 + (wc & 1) * 8192 + (lane & 15) * 128 + g1;

    f32x4 acc[8][4] = {};
    bf16x8 a03[4][2], a47[4][2], b01[2][2], b23[2][2];

#define STAGE_A2(bufoff, t)                                                    \
    do {                                                                       \
        _Pragma("unroll") for (int j = 0; j < 4; ++j)                          \
            gll16(gA2 + (size_t)j * chunkStep + (size_t)(t) * 64,              \
                  ldsA2 + (bufoff) + j * 1024);                                \
    } while (0)
#define STAGE_B2(bufoff, t)                                                    \
    do {                                                                       \
        _Pragma("unroll") for (int j = 0; j < 4; ++j)                          \
            gll16(gB2 + (size_t)j * chunkStep + (size_t)(t) * 64,              \
                  ldsB2 + (bufoff) + j * 1024);                                \
    } while (0)
#define PIN() __builtin_amdgcn_sched_barrier(0)
#define BAR()                              \
    do {                                   \
        PIN();                             \
        __builtin_amdgcn_s_barrier();      \
        PIN();                             \
    } while (0)
#define WAIT_LG12() __builtin_amdgcn_s_waitcnt(0xCC7F)  // lgkmcnt(12)
#define WAIT_LG8() __builtin_amdgcn_s_waitcnt(0xC87F)   // lgkmcnt(8)
#define WAIT_LG0() __builtin_amdgcn_s_waitcnt(0xC07F)   // lgkmcnt(0)
#define WAIT_VM0() __builtin_amdgcn_s_waitcnt(0x0F70)   // vmcnt(0)

    // prologue: tile0 into buf0 (per-wave own halves), full drain once.
    STAGE_A2(0u, 0);
    STAGE_B2(0u, 0);
    WAIT_VM0();
    BAR();

#pragma unroll 1
    for (int i = 0; i < nt; ++i) {
        const unsigned co = (i & 1) ? 32768u : 0u;  // current buf byte offset
        const unsigned no = co ^ 32768u;            // next buf
        const bool full = (i + 1 < nt);
        const unsigned aA0 = rdA0 + co, aA1 = rdA1 + co;
        const unsigned aB0 = rdB0 + co, aB1 = rdB1 + co;

        // ---- issue cluster-1 reads: a03 (8) + b01 (4)
        a03[0][0] = ds_read128o<0>(aA0);
        a03[0][1] = ds_read128o<0>(aA1);
        a03[1][0] = ds_read128o<2048>(aA0);
        a03[1][1] = ds_read128o<2048>(aA1);
        a03[2][0] = ds_read128o<4096>(aA0);
        a03[2][1] = ds_read128o<4096>(aA1);
        a03[3][0] = ds_read128o<6144>(aA0);
        a03[3][1] = ds_read128o<6144>(aA1);
        b01[0][0] = ds_read128o<0>(aB0);
        b01[0][1] = ds_read128o<0>(aB1);
        b01[1][0] = ds_read128o<2048>(aB0);
        b01[1][1] = ds_read128o<2048>(aB1);
        // ---- cluster-2 reads: b23 (4)
        b23[0][0] = ds_read128o<4096>(aB0);
        b23[0][1] = ds_read128o<4096>(aB1);
        b23[1][0] = ds_read128o<6144>(aB0);
        b23[1][1] = ds_read128o<6144>(aB1);
        // ---- cluster-3 reads: a47 (8)
        a47[0][0] = ds_read128o<8192>(aA0);
        a47[0][1] = ds_read128o<8192>(aA1);
        a47[1][0] = ds_read128o<10240>(aA0);
        a47[1][1] = ds_read128o<10240>(aA1);
        a47[2][0] = ds_read128o<12288>(aA0);
        a47[2][1] = ds_read128o<12288>(aA1);
        a47[3][0] = ds_read128o<14336>(aA0);
        a47[3][1] = ds_read128o<14336>(aA1);

        // ---- issue next tile's stages (vmcnt only; ~1 full iter of slack)
        if (full) {
            STAGE_A2(no, i + 1);
            STAGE_B2(no, i + 1);
        }

        __builtin_amdgcn_s_setprio(1);
        // ---- cluster 1: m0-3 x n0-1 (first 12 reads done <=> lgkm<=12)
        WAIT_LG12();
        PIN();
#pragma unroll
        for (int ks = 0; ks < 2; ++ks)
#pragma unroll
            for (int m = 0; m < 4; ++m)
#pragma unroll
                for (int n = 0; n < 2; ++n)
                    acc[m][n] = __builtin_amdgcn_mfma_f32_16x16x32_bf16(
                        a03[m][ks], b01[n][ks], acc[m][n], 0, 0, 0);
        PIN();
        // ---- cluster 2: m0-3 x n2-3 (first 16 done <=> lgkm<=8)
        WAIT_LG8();
        PIN();
#pragma unroll
        for (int ks = 0; ks < 2; ++ks)
#pragma unroll
            for (int m = 0; m < 4; ++m)
#pragma unroll
                for (int n = 0; n < 2; ++n)
                    acc[m][2 + n] = __builtin_amdgcn_mfma_f32_16x16x32_bf16(
                        a03[m][ks], b23[n][ks], acc[m][2 + n], 0, 0, 0);
        PIN();
        // ---- clusters 3+4: m4-7 x n2-3, m4-7 x n0-1 (all reads done)
        WAIT_LG0();
        PIN();
#pragma unroll
        for (int ks = 0; ks < 2; ++ks)
#pragma unroll
            for (int m = 0; m < 4; ++m)
#pragma unroll
                for (int n = 0; n < 2; ++n)
                    acc[4 + m][2 + n] = __builtin_amdgcn_mfma_f32_16x16x32_bf16(
                        a47[m][ks], b23[n][ks], acc[4 + m][2 + n], 0, 0, 0);
#pragma unroll
        for (int ks = 0; ks < 2; ++ks)
#pragma unroll
            for (int m = 0; m < 4; ++m)
#pragma unroll
                for (int n = 0; n < 2; ++n)
                    acc[4 + m][n] = __builtin_amdgcn_mfma_f32_16x16x32_bf16(
                        a47[m][ks], b01[n][ks], acc[4 + m][n], 0, 0, 0);
        __builtin_amdgcn_s_setprio(0);
        PIN();
        // ---- tile boundary: own stages (issued at iter top) must be in LDS
        // before anyone reads buf nxt next iter; then block-wide sync.
        WAIT_VM0();
        BAR();
    }

    // epilogue
    const int orow = brow + wr * 128 + ((lane >> 4) << 2);
    const int ocol = bcol + wc * 64 + (lane & 15);
#pragma unroll
    for (int m = 0; m < 8; ++m) {
#pragma unroll
        for (int j = 0; j < 4; ++j) {
            const int r = orow + m * 16 + j;
            const size_t ro = (size_t)r * Nout;
            if (EPI == 0) {
#pragma unroll
                for (int n = 0; n < 4; ++n) {
                    float v = acc[m][n][j];
                    float u = 1.5957691216057308f * (v + 0.044715f * v * v * v);
                    float g = v / (1.0f + __expf(-u));
                    hOut[ro + ocol + n * 16] = __float2bfloat16(g);
                }
            } else {
                const float sc = s[r];
#pragma unroll
                for (int n = 0; n < 4; ++n)
                    unsafeAtomicAdd(&fOut[ro + ocol + n * 16], sc * acc[m][n][j]);
            }
        }
    }
#undef STAGE_A2
#undef STAGE_B2
#undef PIN
#undef BAR
#undef WAIT_LG12
#undef WAIT_LG8
#undef WAIT_LG0
#undef WAIT_VM0
}

extern "C" void kernel_launch(void* const* d_in, const int* in_sizes, int n_in,
                              void* d_out, int out_size, void* d_ws, size_t ws_size,
                              hipStream_t stream) {
    const float* x = (const float*)d_in[0];
    // d_in[1] = scores (unused), d_in[3] = top_experts (unused)
    const float* ew = (const float*)d_in[2];
    const float* w1 = (const float*)d_in[4];
    const float* w2 = (const float*)d_in[5];
    float* out = (float*)d_out;

    char* ws = (char*)d_ws;
    float* s = (float*)ws;                                                    // 16 KB
    __hip_bfloat16* xb = (__hip_bfloat16*)(ws + 16384);                       // 8 MB
    __hip_bfloat16* w1t = (__hip_bfloat16*)(ws + 16384 + 8388608);            // 16 MB
    __hip_bfloat16* w2t = (__hip_bfloat16*)(ws + 16384 + 8388608 + 16777216); // 16 MB
    __hip_bfloat16* h = (__hip_bfloat16*)(ws + 16384 + 8388608 + 2 * 16777216); // 64 MB

    // merged prep: cast+scale (1024) + w1t (8192) + w2t (8192) + zero-out (1024)
    k_prep<<<1024 + 8192 + 8192 + 1024, 256, 0, stream>>>(x, ew, w1, w2, xb, s, w1t,
                                                          w2t, out);

    // GEMM1: [4096 x 1024] x [1024 x 8192] -> h (gelu, bf16)
    dim3 g1(INTER / 256, TT / 256, 1);  // 32 x 16
    k_gemm1b<0><<<g1, 512, 0, stream>>>(xb, w1t, h, nullptr, nullptr, HID, HID / 64, INTER);

    // GEMM2: [4096 x 8192] x [8192 x 1024] -> out (f32, split-K=4 atomic
    // combine; out zeroed by prep role 3)
    dim3 g2(HID / 256, TT / 256, 4);  // 4 x 16 x 4 = 256 blocks
    k_gemm1b<1><<<g2, 512, 0, stream>>>(h, w2t, nullptr, out, s, INTER, 2048 / 64, HID);
}

// Round 20
// 196.541 us; speedup vs baseline: 1.1075x; 1.0002x over previous
//
#include <hip/hip_runtime.h>
#include <hip/hip_bf16.h>
#include <math.h>

#define HID 1024
#define INTER 8192
#define TT 4096  // tokens = B*S

typedef __bf16 bf16x8 __attribute__((ext_vector_type(8)));
typedef float f32x4 __attribute__((ext_vector_type(4)));

__device__ __forceinline__ void gll16(const void* g, void* l) {
    __builtin_amdgcn_global_load_lds(
        (const __attribute__((address_space(1))) void*)g,
        (__attribute__((address_space(3))) void*)l, 16, 0, 0);
}

// inline-asm LDS read with immediate offset: invisible to SIInsertWaitcnts;
// RAW ordering is ours (counted lgkmcnt/vmcnt + sched_barrier pins).
template <int OFF>
__device__ __forceinline__ bf16x8 ds_read128o(unsigned addr) {
    bf16x8 r;
    asm volatile("ds_read_b128 %0, %1 offset:%c2" : "=v"(r) : "v"(addr), "i"(OFF));
    return r;
}

// ---------------------------------------------------------------------------
// merged prep: role 0 (blocks 0..1023): cast x->bf16 + s[t]=ew0+ew1
//              role 1 (blocks 1024..9215): transpose-cast w1 [1024][8192] -> w1t
//              role 2 (blocks 9216..17407): transpose-cast w2 [8192][1024] -> w2t
//              role 3 (blocks 17408..18431): zero d_out (replaces memset dispatch)
// ---------------------------------------------------------------------------
__device__ __forceinline__ void tcast_tile(const float* __restrict__ in,
                                           __hip_bfloat16* __restrict__ out,
                                           int R, int C, int bx, int by, int tid) {
    __shared__ float tile[32][33];
    const int tx = tid & 31, ty = tid >> 5;  // 32x8
    const int br = by * 32, bc = bx * 32;
#pragma unroll
    for (int j = 0; j < 32; j += 8)
        tile[ty + j][tx] = in[(size_t)(br + ty + j) * C + bc + tx];
    __syncthreads();
#pragma unroll
    for (int j = 0; j < 32; j += 8)
        out[(size_t)(bc + ty + j) * R + br + tx] = __float2bfloat16(tile[tx][ty + j]);
}

__global__ void k_prep(const float* __restrict__ x, const float* __restrict__ ew,
                       const float* __restrict__ w1, const float* __restrict__ w2,
                       __hip_bfloat16* __restrict__ xb, float* __restrict__ s,
                       __hip_bfloat16* __restrict__ w1t, __hip_bfloat16* __restrict__ w2t,
                       float* __restrict__ outZ) {
    const int bid = blockIdx.x, tid = threadIdx.x;
    if (bid < 1024) {
        const int n4 = (TT * HID) / 4;
        const int stride = 1024 * 256;
        for (int i = bid * 256 + tid; i < n4; i += stride) {
            float4 v = ((const float4*)x)[i];
            __hip_bfloat16* o = xb + (size_t)i * 4;
            o[0] = __float2bfloat16(v.x);
            o[1] = __float2bfloat16(v.y);
            o[2] = __float2bfloat16(v.z);
            o[3] = __float2bfloat16(v.w);
        }
        for (int t = bid * 256 + tid; t < TT; t += stride)
            s[t] = ew[2 * t] + ew[2 * t + 1];
    } else if (bid < 1024 + 8192) {
        const int b = bid - 1024;  // w1: R=1024, C=8192 -> bx in [0,256), by in [0,32)
        tcast_tile(w1, w1t, HID, INTER, b % 256, b / 256, tid);
    } else if (bid < 1024 + 8192 + 8192) {
        const int b = bid - (1024 + 8192);  // w2: R=8192, C=1024 -> bx in [0,32), by in [0,256)
        tcast_tile(w2, w2t, INTER, HID, b % 32, b / 32, tid);
    } else {
        // role 3: zero out (GEMM2 atomic-combine target); prep completes
        // before GEMM2 launches (stream order), so this replaces the memset.
        const int zb = bid - (1024 + 8192 + 8192);  // [0,1024)
        float4* o4 = (float4*)outZ;
        const int N4 = (TT * HID) / 4;
        for (int i = zb * 256 + tid; i < N4; i += 1024 * 256)
            o4[i] = make_float4(0.f, 0.f, 0.f, 0.f);
    }
}

// ---------------------------------------------------------------------------
// 256x256 tile, BK=64, 8 waves (2Mx4N). SINGLE-BARRIER pipelined K-loop
// (best-measured config, rounds 12/14/16/18/19: 196.6-199.2 us): per K-tile
// issue 24 ds_read_b128 (cluster-ordered, in-order lgkm FIFO) + 8 own-chunk
// gll16 stages (buf nxt) up front; 4 MFMA clusters gated by counted
// lgkmcnt(12/8/0); one per-wave vmcnt(0) (own stages) + one s_barrier per
// K-tile.
// STAGER = READER chunk map: wave stages exactly the A-half / B-half it
// reads -> per-wave vmcnt ledger is self-contained.
// XOR swizzle on pre-swizzled global source + swizzled LDS read (rule #21).
// EPI=0: gelu -> bf16 hOut.  EPI=1: unsafeAtomicAdd(s[row]*acc) into fOut.
// ---------------------------------------------------------------------------
template <int EPI>
__global__ __launch_bounds__(512, 2) void k_gemm1b(
    const __hip_bfloat16* __restrict__ A, const __hip_bfloat16* __restrict__ Bt,
    __hip_bfloat16* __restrict__ hOut, float* __restrict__ fOut,
    const float* __restrict__ s, int Kfull, int nt, int Nout) {
    __shared__ __hip_bfloat16 sA[2][2][128][64];  // [buf][half][row][k]
    __shared__ __hip_bfloat16 sB[2][2][128][64];
    const int tid = threadIdx.x;
    const int lane = tid & 63, wid = tid >> 6;
    const int wr = wid >> 2, wc = wid & 3;  // 2x4 wave grid; wave tile 128x64

    // XCD-bijective swizzle; nwg % 8 == 0 by construction.
    const int nwg = gridDim.x * gridDim.y;
    const int wg = blockIdx.y * gridDim.x + blockIdx.x;
    const int swz = (wg & 7) * (nwg >> 3) + (wg >> 3);
    const int brow = (swz / gridDim.x) * 256;
    const int bcol = (swz % gridDim.x) * 256;
    const size_t kbase = (size_t)blockIdx.z * ((size_t)nt * 64);

    // --- per-wave staging (stager = reader) ---
    // chunk = 8 rows x 64 cols = 1KB; lane covers row 8q+(lane>>3), granule
    // (lane&7), source granule pre-XOR'd by row&7 (= lane>>3).
    const int colsw = (((lane & 7) ^ (lane >> 3)) << 3);  // elements
    const int qA0 = (wid & 3) * 4;                        // A chunk base
    const int bh = (wid >> 1) & 1;                        // B half this wave reads
    const int qB0 = ((wid & 1) | ((wid >> 2) << 1)) * 4;  // B chunk base
    const __hip_bfloat16* gA2 =
        A + (size_t)(brow + wr * 128 + qA0 * 8 + (lane >> 3)) * Kfull + kbase + colsw;
    const __hip_bfloat16* gB2 =
        Bt + (size_t)(bcol + bh * 128 + qB0 * 8 + (lane >> 3)) * Kfull + kbase + colsw;
    char* ldsA2 = (char*)&sA[0][0][0][0] + wr * 16384 + qA0 * 1024;
    char* ldsB2 = (char*)&sB[0][0][0][0] + bh * 16384 + qB0 * 1024;
    const size_t chunkStep = (size_t)8 * Kfull;

    // read-side swizzled LDS byte addresses (32-bit, for asm ds_read)
    const unsigned baseA = (unsigned)(uintptr_t)&sA[0][0][0][0];
    const unsigned baseB = (unsigned)(uintptr_t)&sB[0][0][0][0];
    const unsigned g0 = (((lane >> 4)) ^ (lane & 7)) << 4;
    const unsigned g1 = ((4 + (lane >> 4)) ^ (lane & 7)) << 4;
    const unsigned rdA0 = baseA + wr * 16384 + (lane & 15) * 128 + g0;
    const unsigned rdA1 = baseA + wr * 16384 + (lane & 15) * 128 + g1;
    const unsigned rdB0 = baseB + (wc >> 1) * 16384 + (wc & 1) * 8192 + (lane & 15) * 128 + g0;
    const unsigned rdB1 = baseB + (wc >> 1) * 16384 + (wc & 1) * 8192 + (lane & 15) * 128 + g1;

    f32x4 acc[8][4] = {};
    bf16x8 a03[4][2], a47[4][2], b01[2][2], b23[2][2];

#define STAGE_A2(bufoff, t)                                                    \
    do {                                                                       \
        _Pragma("unroll") for (int j = 0; j < 4; ++j)                          \
            gll16(gA2 + (size_t)j * chunkStep + (size_t)(t) * 64,              \
                  ldsA2 + (bufoff) + j * 1024);                                \
    } while (0)
#define STAGE_B2(bufoff, t)                                                    \
    do {                                                                       \
        _Pragma("unroll") for (int j = 0; j < 4; ++j)                          \
            gll16(gB2 + (size_t)j * chunkStep + (size_t)(t) * 64,              \
                  ldsB2 + (bufoff) + j * 1024);                                \
    } while (0)
#define PIN() __builtin_amdgcn_sched_barrier(0)
#define BAR()                              \
    do {                                   \
        PIN();                             \
        __builtin_amdgcn_s_barrier();      \
        PIN();                             \
    } while (0)
#define WAIT_LG12() __builtin_amdgcn_s_waitcnt(0xCC7F)  // lgkmcnt(12)
#define WAIT_LG8() __builtin_amdgcn_s_waitcnt(0xC87F)   // lgkmcnt(8)
#define WAIT_LG0() __builtin_amdgcn_s_waitcnt(0xC07F)   // lgkmcnt(0)
#define WAIT_VM0() __builtin_amdgcn_s_waitcnt(0x0F70)   // vmcnt(0)

    // prologue: tile0 into buf0 (per-wave own halves), full drain once.
    STAGE_A2(0u, 0);
    STAGE_B2(0u, 0);
    WAIT_VM0();
    BAR();

#pragma unroll 1
    for (int i = 0; i < nt; ++i) {
        const unsigned co = (i & 1) ? 32768u : 0u;  // current buf byte offset
        const unsigned no = co ^ 32768u;            // next buf
        const bool full = (i + 1 < nt);
        const unsigned aA0 = rdA0 + co, aA1 = rdA1 + co;
        const unsigned aB0 = rdB0 + co, aB1 = rdB1 + co;

        // ---- issue cluster-1 reads: a03 (8) + b01 (4)
        a03[0][0] = ds_read128o<0>(aA0);
        a03[0][1] = ds_read128o<0>(aA1);
        a03[1][0] = ds_read128o<2048>(aA0);
        a03[1][1] = ds_read128o<2048>(aA1);
        a03[2][0] = ds_read128o<4096>(aA0);
        a03[2][1] = ds_read128o<4096>(aA1);
        a03[3][0] = ds_read128o<6144>(aA0);
        a03[3][1] = ds_read128o<6144>(aA1);
        b01[0][0] = ds_read128o<0>(aB0);
        b01[0][1] = ds_read128o<0>(aB1);
        b01[1][0] = ds_read128o<2048>(aB0);
        b01[1][1] = ds_read128o<2048>(aB1);
        // ---- cluster-2 reads: b23 (4)
        b23[0][0] = ds_read128o<4096>(aB0);
        b23[0][1] = ds_read128o<4096>(aB1);
        b23[1][0] = ds_read128o<6144>(aB0);
        b23[1][1] = ds_read128o<6144>(aB1);
        // ---- cluster-3 reads: a47 (8)
        a47[0][0] = ds_read128o<8192>(aA0);
        a47[0][1] = ds_read128o<8192>(aA1);
        a47[1][0] = ds_read128o<10240>(aA0);
        a47[1][1] = ds_read128o<10240>(aA1);
        a47[2][0] = ds_read128o<12288>(aA0);
        a47[2][1] = ds_read128o<12288>(aA1);
        a47[3][0] = ds_read128o<14336>(aA0);
        a47[3][1] = ds_read128o<14336>(aA1);

        // ---- issue next tile's stages (vmcnt only; ~1 full iter of slack)
        if (full) {
            STAGE_A2(no, i + 1);
            STAGE_B2(no, i + 1);
        }

        __builtin_amdgcn_s_setprio(1);
        // ---- cluster 1: m0-3 x n0-1 (first 12 reads done <=> lgkm<=12)
        WAIT_LG12();
        PIN();
#pragma unroll
        for (int ks = 0; ks < 2; ++ks)
#pragma unroll
            for (int m = 0; m < 4; ++m)
#pragma unroll
                for (int n = 0; n < 2; ++n)
                    acc[m][n] = __builtin_amdgcn_mfma_f32_16x16x32_bf16(
                        a03[m][ks], b01[n][ks], acc[m][n], 0, 0, 0);
        PIN();
        // ---- cluster 2: m0-3 x n2-3 (first 16 done <=> lgkm<=8)
        WAIT_LG8();
        PIN();
#pragma unroll
        for (int ks = 0; ks < 2; ++ks)
#pragma unroll
            for (int m = 0; m < 4; ++m)
#pragma unroll
                for (int n = 0; n < 2; ++n)
                    acc[m][2 + n] = __builtin_amdgcn_mfma_f32_16x16x32_bf16(
                        a03[m][ks], b23[n][ks], acc[m][2 + n], 0, 0, 0);
        PIN();
        // ---- clusters 3+4: m4-7 x n2-3, m4-7 x n0-1 (all reads done)
        WAIT_LG0();
        PIN();
#pragma unroll
        for (int ks = 0; ks < 2; ++ks)
#pragma unroll
            for (int m = 0; m < 4; ++m)
#pragma unroll
                for (int n = 0; n < 2; ++n)
                    acc[4 + m][2 + n] = __builtin_amdgcn_mfma_f32_16x16x32_bf16(
                        a47[m][ks], b23[n][ks], acc[4 + m][2 + n], 0, 0, 0);
#pragma unroll
        for (int ks = 0; ks < 2; ++ks)
#pragma unroll
            for (int m = 0; m < 4; ++m)
#pragma unroll
                for (int n = 0; n < 2; ++n)
                    acc[4 + m][n] = __builtin_amdgcn_mfma_f32_16x16x32_bf16(
                        a47[m][ks], b01[n][ks], acc[4 + m][n], 0, 0, 0);
        __builtin_amdgcn_s_setprio(0);
        PIN();
        // ---- tile boundary: own stages (issued at iter top) must be in LDS
        // before anyone reads buf nxt next iter; then block-wide sync.
        WAIT_VM0();
        BAR();
    }

    // epilogue
    const int orow = brow + wr * 128 + ((lane >> 4) << 2);
    const int ocol = bcol + wc * 64 + (lane & 15);
#pragma unroll
    for (int m = 0; m < 8; ++m) {
#pragma unroll
        for (int j = 0; j < 4; ++j) {
            const int r = orow + m * 16 + j;
            const size_t ro = (size_t)r * Nout;
            if (EPI == 0) {
#pragma unroll
                for (int n = 0; n < 4; ++n) {
                    float v = acc[m][n][j];
                    float u = 1.5957691216057308f * (v + 0.044715f * v * v * v);
                    float g = v / (1.0f + __expf(-u));
                    hOut[ro + ocol + n * 16] = __float2bfloat16(g);
                }
            } else {
                const float sc = s[r];
#pragma unroll
                for (int n = 0; n < 4; ++n)
                    unsafeAtomicAdd(&fOut[ro + ocol + n * 16], sc * acc[m][n][j]);
            }
        }
    }
#undef STAGE_A2
#undef STAGE_B2
#undef PIN
#undef BAR
#undef WAIT_LG12
#undef WAIT_LG8
#undef WAIT_LG0
#undef WAIT_VM0
}

extern "C" void kernel_launch(void* const* d_in, const int* in_sizes, int n_in,
                              void* d_out, int out_size, void* d_ws, size_t ws_size,
                              hipStream_t stream) {
    const float* x = (const float*)d_in[0];
    // d_in[1] = scores (unused), d_in[3] = top_experts (unused)
    const float* ew = (const float*)d_in[2];
    const float* w1 = (const float*)d_in[4];
    const float* w2 = (const float*)d_in[5];
    float* out = (float*)d_out;

    char* ws = (char*)d_ws;
    float* s = (float*)ws;                                                    // 16 KB
    __hip_bfloat16* xb = (__hip_bfloat16*)(ws + 16384);                       // 8 MB
    __hip_bfloat16* w1t = (__hip_bfloat16*)(ws + 16384 + 8388608);            // 16 MB
    __hip_bfloat16* w2t = (__hip_bfloat16*)(ws + 16384 + 8388608 + 16777216); // 16 MB
    __hip_bfloat16* h = (__hip_bfloat16*)(ws + 16384 + 8388608 + 2 * 16777216); // 64 MB

    // merged prep: cast+scale (1024) + w1t (8192) + w2t (8192) + zero-out (1024)
    k_prep<<<1024 + 8192 + 8192 + 1024, 256, 0, stream>>>(x, ew, w1, w2, xb, s, w1t,
                                                          w2t, out);

    // GEMM1: [4096 x 1024] x [1024 x 8192] -> h (gelu, bf16)
    dim3 g1(INTER / 256, TT / 256, 1);  // 32 x 16
    k_gemm1b<0><<<g1, 512, 0, stream>>>(xb, w1t, h, nullptr, nullptr, HID, HID / 64, INTER);

    // GEMM2: [4096 x 8192] x [8192 x 1024] -> out (f32, split-K=4 atomic
    // combine; out zeroed by prep role 3)
    dim3 g2(HID / 256, TT / 256, 4);  // 4 x 16 x 4 = 256 blocks
    k_gemm1b<1><<<g2, 512, 0, stream>>>(h, w2t, nullptr, out, s, INTER, 2048 / 64, HID);
}